// Round 18
// baseline (352.044 us; speedup 1.0000x reference)
//
#include <hip/hip_runtime.h>
#include <hip/hip_fp16.h>
#include <hip/hip_cooperative_groups.h>

namespace cg = cooperative_groups;

#define N_NODES 50000
#define E_EDGES 800000
#define ETOT    (E_EDGES + N_NODES)   // edges + self loops = 850000
#define NF      128
#define HEADS   4
#define NC      32
#define LOG2E   1.44269504088896340736f
#define ASTRIDE 136                   // Abf row stride (ushort)
#define CAP     96                    // padded CSR row capacity (mean deg 17; P(deg>=96)~1e-39)

// radix CSR build
#define NBUCK   196                   // dst>>8 buckets (49999>>8 = 195)
#define EPB     4096                  // edges per block in passes A/C
#define NBLKA   ((ETOT + EPB - 1) / EPB)          // 208
#define PARTN   (NBUCK * NBLKA)                   // 40768
#define NBLKS   ((PARTN + 255) / 256)             // 160
#define WCB     65                                // wconv blocks per layer
#define COOPB   (NBLKA + 2 * WCB)                 // 338 blocks, trivially co-resident

typedef __attribute__((ext_vector_type(8))) short short8v;
typedef __attribute__((ext_vector_type(4))) float f32x4;

__device__ inline ushort rne_bf16(float x) {
    uint u = __float_as_uint(x);
    return (ushort)((u + 0x7fff + ((u >> 16) & 1)) >> 16);
}
__device__ inline float h2f_lo(uint u) { return __half2float(__ushort_as_half((ushort)(u & 0xffffu))); }
__device__ inline float h2f_hi(uint u) { return __half2float(__ushort_as_half((ushort)(u >> 16))); }

// ---------------- wconv body: Wt[n][k] = bf16(W[k][n]) [144][144]; att folded rows ----------------
__device__ inline void wconv_body(int wb, int tid, const float* __restrict__ W,
                                  const float* __restrict__ att_src,
                                  const float* __restrict__ att_dst,
                                  ushort* __restrict__ Wt) {
    if (wb < 64) {
        int i = wb * 256 + tid;       // i = k*128 + n
        int k = i >> 7, n = i & 127;
        Wt[n * 144 + k] = rne_bf16(W[i]);
    } else {
        for (int j = tid; j < 1024; j += 256) {
            int k = j >> 3, o = j & 7;
            int h = o & 3;
            const float* av = (o < 4) ? att_src : att_dst;
            float s = 0.f;
            #pragma unroll
            for (int c = 0; c < 32; ++c) s += W[k * 128 + h * 32 + c] * av[h * 32 + c];
            Wt[(128 + o) * 144 + k] = rne_bf16(s * LOG2E);
        }
        for (int j = tid; j < 8 * 144; j += 256)
            Wt[(136 + (j / 144)) * 144 + (j % 144)] = 0;
    }
}

// in-block inclusive scan over 256 threads (wave shfl + LDS cross-wave)
__device__ inline int block_incl_scan(int v, int* sh4) {
    int lane = threadIdx.x & 63, wid = threadIdx.x >> 6;
    int s = v;
    #pragma unroll
    for (int ofs = 1; ofs < 64; ofs <<= 1) {
        int t = __shfl_up(s, ofs);
        if (lane >= ofs) s += t;
    }
    if (lane == 63) sh4[wid] = s;
    __syncthreads();
    int add = 0;
    #pragma unroll
    for (int k = 0; k < 3; ++k) if (k < wid) add += sh4[k];
    return s + add;
}

// ---------------- cooperative CSR build: 6 former dispatches, 1 launch, 5 grid syncs ----------------
__global__ __launch_bounds__(256) void csr_coop_kernel(const int* __restrict__ adj,
                                                       int* __restrict__ partials,
                                                       const float* __restrict__ W1,
                                                       const float* __restrict__ as1,
                                                       const float* __restrict__ ad1,
                                                       ushort* __restrict__ Wt1,
                                                       const float* __restrict__ W2,
                                                       const float* __restrict__ as2,
                                                       const float* __restrict__ ad2,
                                                       ushort* __restrict__ Wt2,
                                                       int* __restrict__ bsum,
                                                       int* __restrict__ bofs,
                                                       int* __restrict__ pscan,
                                                       int2* __restrict__ ebuf,
                                                       int* __restrict__ cnt,
                                                       int* __restrict__ slots) {
    cg::grid_group grid = cg::this_grid();
    __shared__ int lc[256];            // hist/scatter use [0..NBUCK); build uses [0..256)
    __shared__ int sh4[4];
    int b = blockIdx.x, tid = threadIdx.x;

    // ---- P1: bucket histogram (blocks 0..207) | wconv (blocks 208..337) ----
    if (b < NBLKA) {
        for (int i = tid; i < NBUCK; i += 256) lc[i] = 0;
        __syncthreads();
        int base = b * EPB;
        #pragma unroll
        for (int i = 0; i < EPB / 256; ++i) {
            int e = base + i * 256 + tid;
            if (e < ETOT) {
                int dst = (e < E_EDGES) ? adj[E_EDGES + e] : (e - E_EDGES);
                atomicAdd(&lc[dst >> 8], 1);
            }
        }
        __syncthreads();
        for (int i = tid; i < NBUCK; i += 256) partials[i * NBLKA + b] = lc[i];
    } else {
        int wb = b - NBLKA;
        if (wb < WCB) wconv_body(wb, tid, W1, as1, ad1, Wt1);
        else          wconv_body(wb - WCB, tid, W2, as2, ad2, Wt2);
    }
    grid.sync();

    // ---- P2: per-256-chunk sums ----
    if (b < NBLKS) {
        int i = b * 256 + tid;
        int v = (i < PARTN) ? partials[i] : 0;
        int s = block_incl_scan(v, sh4);
        if (tid == 255) bsum[b] = s;
    }
    grid.sync();

    // ---- P3: exclusive scan of block sums (single block) ----
    if (b == 0) {
        int v = (tid < NBLKS) ? bsum[tid] : 0;
        int s = block_incl_scan(v, sh4);
        if (tid < NBLKS) bofs[tid] = s - v;
    }
    grid.sync();

    // ---- P4: final exclusive scan -> pscan ----
    if (b < NBLKS) {
        int i = b * 256 + tid;
        int v = (i < PARTN) ? partials[i] : 0;
        int s = block_incl_scan(v, sh4);
        if (i < PARTN) pscan[i] = bofs[b] + s - v;
    }
    grid.sync();

    // ---- P5: scatter edges into bucket-sorted ebuf via LDS ranks ----
    if (b < NBLKA) {
        for (int i = tid; i < NBUCK; i += 256) lc[i] = 0;
        __syncthreads();
        int base = b * EPB;
        #pragma unroll
        for (int i = 0; i < EPB / 256; ++i) {
            int e = base + i * 256 + tid;
            if (e < ETOT) {
                int src, dst;
                if (e < E_EDGES) { src = adj[e]; dst = adj[E_EDGES + e]; }
                else             { src = dst = e - E_EDGES; }
                int bk = dst >> 8;
                int r = atomicAdd(&lc[bk], 1);
                ebuf[pscan[bk * NBLKA + b] + r] = make_int2(src, dst);
            }
        }
    }
    grid.sync();

    // ---- P6: per-bucket dst ranks -> cnt + slots ----
    if (b < NBUCK) {
        lc[tid] = 0;
        __syncthreads();
        int base = pscan[b * NBLKA];
        int end  = (b == NBUCK - 1) ? ETOT : pscan[(b + 1) * NBLKA];
        for (int e = base + tid; e < end; e += 256) {
            int2 sd = ebuf[e];
            int d = sd.y & 255;
            int r = atomicAdd(&lc[d], 1);
            slots[(size_t)sd.y * CAP + r] = sd.x;
        }
        __syncthreads();
        int dst = b * 256 + tid;
        if (dst < N_NODES) cnt[dst] = lc[tid];
    }
}

// ---------------- MFMA GEMM: Hf = f16(X @ W); a_s/a_d from folded att columns ----------------
template<bool BF16IN>
__global__ __launch_bounds__(256) void gemm_mfma_kernel(const void* __restrict__ Xv_,
                                                        const ushort* __restrict__ Wt,
                                                        ushort* __restrict__ Hf,
                                                        float* __restrict__ a_s,
                                                        float* __restrict__ a_d, int nrows) {
    __shared__ ushort Abf[64 * ASTRIDE];
    int tid = threadIdx.x;
    int r0 = blockIdx.x * 64;
    int rleft = nrows - r0;

    if (BF16IN) {
        const uint4* Xv = (const uint4*)((const ushort*)Xv_ + (size_t)r0 * NF);  // 8 bf16/uint4
        #pragma unroll
        for (int p = 0; p < 4; ++p) {
            int i = p * 256 + tid;
            int row = i >> 4, c8 = i & 15;
            uint4 v = (row < rleft) ? Xv[row * 16 + c8] : make_uint4(0u, 0u, 0u, 0u);
            *(uint4*)&Abf[row * ASTRIDE + c8 * 8] = v;
        }
    } else {
        const float4* Xv = (const float4*)((const float*)Xv_ + (size_t)r0 * NF);
        #pragma unroll
        for (int p = 0; p < 8; ++p) {
            int i = p * 256 + tid;
            int row = i >> 5, c4 = i & 31;
            float4 v = (row < rleft) ? Xv[row * 32 + c4] : make_float4(0.f, 0.f, 0.f, 0.f);
            ushort4 hv;
            hv.x = rne_bf16(v.x); hv.y = rne_bf16(v.y);
            hv.z = rne_bf16(v.z); hv.w = rne_bf16(v.w);
            *(ushort4*)&Abf[row * ASTRIDE + c4 * 4] = hv;
        }
    }
    __syncthreads();

    int wv = tid >> 6;
    int l = tid & 63;
    int lr = l & 15;
    int lk = l >> 4;
    int rowb = wv * 16;

    short8v a[4];
    #pragma unroll
    for (int kc = 0; kc < 4; ++kc)
        a[kc] = *(const short8v*)&Abf[(rowb + lr) * ASTRIDE + kc * 32 + lk * 8];

    f32x4 acc[9];
    #pragma unroll
    for (int ct = 0; ct < 9; ++ct) acc[ct] = (f32x4){0.f, 0.f, 0.f, 0.f};

    #pragma unroll
    for (int ct = 0; ct < 9; ++ct) {
        #pragma unroll
        for (int kc = 0; kc < 4; ++kc) {
            short8v b = *(const short8v*)&Wt[(ct * 16 + lr) * 144 + kc * 32 + lk * 8];
            acc[ct] = __builtin_amdgcn_mfma_f32_16x16x32_bf16(a[kc], b, acc[ct], 0, 0, 0);
        }
    }

    int rbase = r0 + rowb + lk * 4;
    #pragma unroll
    for (int ct = 0; ct < 8; ++ct) {
        int col = ct * 16 + lr;
        #pragma unroll
        for (int ri = 0; ri < 4; ++ri) {
            int r = rbase + ri;
            if (r < nrows) Hf[(size_t)r * NF + col] = __half_as_ushort(__float2half(acc[ct][ri]));
        }
    }
    if (lr < 8) {
        #pragma unroll
        for (int ri = 0; ri < 4; ++ri) {
            int r = rbase + ri;
            if (r < nrows) {
                if (lr < 4) a_s[(size_t)r * 4 + lr] = acc[8][ri];
                else        a_d[(size_t)r * 4 + (lr - 4)] = acc[8][ri];
            }
        }
    }
}

// ---------------- per-node softmax + aggregation, quarter-per-edge, granule 8 ----------------
template<int WRITE_BF16>
__global__ __launch_bounds__(256) void agg_kernel(const ushort* __restrict__ Hf,
                                                  const float* __restrict__ a_s,
                                                  const float* __restrict__ a_d,
                                                  const int* __restrict__ cnt,
                                                  const int* __restrict__ slots,
                                                  const float* __restrict__ bias,
                                                  void* __restrict__ Out) {
    int lane = threadIdx.x & 63;
    int node = blockIdx.x * 4 + (threadIdx.x >> 6);
    if (node >= N_NODES) return;
    int q = lane >> 4;
    int t = lane & 15;
    int h = t >> 2;
    float adn = a_d[node * 4 + h];
    int deg = cnt[node];
    const int* row = slots + (size_t)node * CAP;
    const uint4* H4 = (const uint4*)Hf;
    float acc[8];
    #pragma unroll
    for (int k = 0; k < 8; ++k) acc[k] = 0.f;
    float denom = 0.f;

    for (int j = 0; j < deg; j += 8) {
        int sv[2]; float ev[2]; uint4 hv[2]; bool ok[2];
        #pragma unroll
        for (int u = 0; u < 2; ++u) {
            int idx = j + u * 4 + q;
            ok[u] = idx < deg;
            sv[u] = row[ok[u] ? idx : 0];
        }
        #pragma unroll
        for (int u = 0; u < 2; ++u) ev[u] = a_s[sv[u] * 4 + h];
        #pragma unroll
        for (int u = 0; u < 2; ++u) hv[u] = H4[(size_t)sv[u] * 16 + t];
        #pragma unroll
        for (int u = 0; u < 2; ++u) {
            float e = ev[u] + adn;
            e = (e > 0.f) ? e : 0.2f * e;          // leaky_relu (log2e scale commutes)
            float w = ok[u] ? exp2f(e) : 0.f;      // |e| small; no max-subtraction needed
            denom += w;
            acc[0] = fmaf(h2f_lo(hv[u].x), w, acc[0]);
            acc[1] = fmaf(h2f_hi(hv[u].x), w, acc[1]);
            acc[2] = fmaf(h2f_lo(hv[u].y), w, acc[2]);
            acc[3] = fmaf(h2f_hi(hv[u].y), w, acc[3]);
            acc[4] = fmaf(h2f_lo(hv[u].z), w, acc[4]);
            acc[5] = fmaf(h2f_hi(hv[u].z), w, acc[5]);
            acc[6] = fmaf(h2f_lo(hv[u].w), w, acc[6]);
            acc[7] = fmaf(h2f_hi(hv[u].w), w, acc[7]);
        }
    }
    #pragma unroll
    for (int ofs = 16; ofs < 64; ofs <<= 1) {
        denom += __shfl_xor(denom, ofs);
        #pragma unroll
        for (int k = 0; k < 8; ++k) acc[k] += __shfl_xor(acc[k], ofs);
    }
    if (q == 0) {
        float inv = 1.f / (denom + 1e-16f);
        float4 b0 = ((const float4*)bias)[t * 2];
        float4 b1 = ((const float4*)bias)[t * 2 + 1];
        float v0 = acc[0] * inv + b0.x, v1 = acc[1] * inv + b0.y;
        float v2 = acc[2] * inv + b0.z, v3 = acc[3] * inv + b0.w;
        float v4 = acc[4] * inv + b1.x, v5 = acc[5] * inv + b1.y;
        float v6 = acc[6] * inv + b1.z, v7 = acc[7] * inv + b1.w;
        if (WRITE_BF16) {
            v0 = fmaxf(v0, 0.f); v1 = fmaxf(v1, 0.f); v2 = fmaxf(v2, 0.f); v3 = fmaxf(v3, 0.f);
            v4 = fmaxf(v4, 0.f); v5 = fmaxf(v5, 0.f); v6 = fmaxf(v6, 0.f); v7 = fmaxf(v7, 0.f);
            uint4 pv;
            pv.x = (uint)rne_bf16(v0) | ((uint)rne_bf16(v1) << 16);
            pv.y = (uint)rne_bf16(v2) | ((uint)rne_bf16(v3) << 16);
            pv.z = (uint)rne_bf16(v4) | ((uint)rne_bf16(v5) << 16);
            pv.w = (uint)rne_bf16(v6) | ((uint)rne_bf16(v7) << 16);
            ((uint4*)((ushort*)Out + (size_t)node * NF))[t] = pv;
        } else {
            float4* orow = (float4*)((float*)Out + (size_t)node * NF);
            orow[t * 2]     = make_float4(v0, v1, v2, v3);
            orow[t * 2 + 1] = make_float4(v4, v5, v6, v7);
        }
    }
}

extern "C" void kernel_launch(void* const* d_in, const int* in_sizes, int n_in,
                              void* d_out, int out_size, void* d_ws, size_t ws_size,
                              hipStream_t stream) {
    const float* x        = (const float*)d_in[0];
    const int*   adj      = (const int*)  d_in[1];
    const float* W1       = (const float*)d_in[2];
    const float* att_src1 = (const float*)d_in[3];
    const float* att_dst1 = (const float*)d_in[4];
    const float* b1       = (const float*)d_in[5];
    const float* W2       = (const float*)d_in[6];
    const float* att_src2 = (const float*)d_in[7];
    const float* att_dst2 = (const float*)d_in[8];
    const float* b2       = (const float*)d_in[9];
    float* out = (float*)d_out;

    // workspace layout
    float* a_s  = (float*)d_ws;                            // N*4
    float* a_d  = a_s + (size_t)N_NODES * HEADS;           // N*4
    ushort* Hf  = (ushort*)(a_d + (size_t)N_NODES * HEADS);// N*128 f16
    ushort* obf = Hf + (size_t)N_NODES * NF;               // N*128 bf16 (inter-layer)
    ushort* Wt1 = obf + (size_t)N_NODES * NF;              // 144*144 bf16
    ushort* Wt2 = Wt1 + 144 * 144;                         // 144*144 bf16
    int* cnt     = (int*)(Wt2 + 144 * 144);                // N
    int* slots   = cnt + N_NODES;                          // N*CAP
    int* partials= slots + (size_t)N_NODES * CAP;          // PARTN
    int* pscan   = partials + PARTN;                       // PARTN
    int* bsum    = pscan + PARTN;                          // NBLKS
    int* bofs    = bsum + NBLKS;                           // NBLKS
    int2* ebuf   = (int2*)(bofs + NBLKS + 2);              // ETOT (8B aligned)

    // K1 (cooperative): hist | wconv1 | wconv2 -> scan -> scatter -> build
    {
        void* args[] = {(void*)&adj, (void*)&partials,
                        (void*)&W1, (void*)&att_src1, (void*)&att_dst1, (void*)&Wt1,
                        (void*)&W2, (void*)&att_src2, (void*)&att_dst2, (void*)&Wt2,
                        (void*)&bsum, (void*)&bofs, (void*)&pscan,
                        (void*)&ebuf, (void*)&cnt, (void*)&slots};
        hipLaunchCooperativeKernel((const void*)csr_coop_kernel, dim3(COOPB), dim3(256),
                                   args, 0, stream);
    }

    // ---- layer 1 ----
    gemm_mfma_kernel<false><<<(N_NODES + 63) / 64, 256, 0, stream>>>(x, Wt1, Hf, a_s, a_d, N_NODES);
    agg_kernel<1><<<(N_NODES + 3) / 4, 256, 0, stream>>>(Hf, a_s, a_d, cnt, slots, b1, obf);

    // ---- layer 2 ----
    gemm_mfma_kernel<true><<<(N_NODES + 63) / 64, 256, 0, stream>>>(obf, Wt2, Hf, a_s, a_d, N_NODES);
    agg_kernel<0><<<(N_NODES + 3) / 4, 256, 0, stream>>>(Hf, a_s, a_d, cnt, slots, b2, out);
}

// Round 19
// 140.146 us; speedup vs baseline: 2.5120x; 2.5120x over previous
//
#include <hip/hip_runtime.h>
#include <hip/hip_fp16.h>

#define N_NODES 50000
#define E_EDGES 800000
#define ETOT    (E_EDGES + N_NODES)   // edges + self loops = 850000
#define NF      128
#define HEADS   4
#define NC      32
#define LOG2E   1.44269504088896340736f
#define ASTRIDE 136                   // Abf row stride (ushort)
#define CAP     96                    // padded CSR row capacity (mean deg 17; P(deg>=96)~1e-39)

// radix CSR build
#define NBUCK   196                   // dst>>8 buckets (49999>>8 = 195)
#define EPB     4096                  // edges per block in passes A/C
#define NBLKA   ((ETOT + EPB - 1) / EPB)          // 208
#define PARTN   (NBUCK * NBLKA)                   // 40768
#define NBLKS   ((PARTN + 255) / 256)             // 160
#define WCB     65                                // wconv blocks per layer

typedef __attribute__((ext_vector_type(8))) short short8v;
typedef __attribute__((ext_vector_type(4))) float f32x4;

__device__ inline ushort rne_bf16(float x) {
    uint u = __float_as_uint(x);
    return (ushort)((u + 0x7fff + ((u >> 16) & 1)) >> 16);
}
__device__ inline float h2f_lo(uint u) { return __half2float(__ushort_as_half((ushort)(u & 0xffffu))); }
__device__ inline float h2f_hi(uint u) { return __half2float(__ushort_as_half((ushort)(u >> 16))); }

// ---------------- wconv body: Wt[n][k] = bf16(W[k][n]) [144][144]; att folded rows ----------------
__device__ inline void wconv_body(int wb, int tid, const float* __restrict__ W,
                                  const float* __restrict__ att_src,
                                  const float* __restrict__ att_dst,
                                  ushort* __restrict__ Wt) {
    if (wb < 64) {
        int i = wb * 256 + tid;       // i = k*128 + n
        int k = i >> 7, n = i & 127;
        Wt[n * 144 + k] = rne_bf16(W[i]);
    } else {
        for (int j = tid; j < 1024; j += 256) {
            int k = j >> 3, o = j & 7;
            int h = o & 3;
            const float* av = (o < 4) ? att_src : att_dst;
            float s = 0.f;
            #pragma unroll
            for (int c = 0; c < 32; ++c) s += W[k * 128 + h * 32 + c] * av[h * 32 + c];
            Wt[(128 + o) * 144 + k] = rne_bf16(s * LOG2E);
        }
        for (int j = tid; j < 8 * 144; j += 256)
            Wt[(136 + (j / 144)) * 144 + (j % 144)] = 0;
    }
}

// ---------------- K1: bucket hist(208) | wconv1(65) | wconv2(65) ----------------
__global__ __launch_bounds__(256) void prep_kernel(const int* __restrict__ adj,
                                                   int* __restrict__ partials,
                                                   const float* __restrict__ W1,
                                                   const float* __restrict__ as1,
                                                   const float* __restrict__ ad1,
                                                   ushort* __restrict__ Wt1,
                                                   const float* __restrict__ W2,
                                                   const float* __restrict__ as2,
                                                   const float* __restrict__ ad2,
                                                   ushort* __restrict__ Wt2) {
    __shared__ int lc[NBUCK];
    int b = blockIdx.x, tid = threadIdx.x;
    if (b < NBLKA) {
        for (int i = tid; i < NBUCK; i += 256) lc[i] = 0;
        __syncthreads();
        int base = b * EPB;
        #pragma unroll
        for (int i = 0; i < EPB / 256; ++i) {
            int e = base + i * 256 + tid;
            if (e < ETOT) {
                int dst = (e < E_EDGES) ? adj[E_EDGES + e] : (e - E_EDGES);
                atomicAdd(&lc[dst >> 8], 1);
            }
        }
        __syncthreads();
        for (int i = tid; i < NBUCK; i += 256) partials[i * NBLKA + b] = lc[i];
    } else {
        int wb = b - NBLKA;
        if (wb < WCB) wconv_body(wb, tid, W1, as1, ad1, Wt1);
        else          wconv_body(wb - WCB, tid, W2, as2, ad2, Wt2);
    }
}

// in-block inclusive scan over 256 threads (wave shfl + LDS cross-wave)
__device__ inline int block_incl_scan(int v, int* sh4) {
    int lane = threadIdx.x & 63, wid = threadIdx.x >> 6;
    int s = v;
    #pragma unroll
    for (int ofs = 1; ofs < 64; ofs <<= 1) {
        int t = __shfl_up(s, ofs);
        if (lane >= ofs) s += t;
    }
    if (lane == 63) sh4[wid] = s;
    __syncthreads();
    int add = 0;
    #pragma unroll
    for (int k = 0; k < 3; ++k) if (k < wid) add += sh4[k];
    return s + add;
}

__global__ __launch_bounds__(256) void bsum2_kernel(const int* __restrict__ partials,
                                                    int* __restrict__ bsum) {
    __shared__ int sh4[4];
    int i = blockIdx.x * 256 + threadIdx.x;
    int v = (i < PARTN) ? partials[i] : 0;
    int s = block_incl_scan(v, sh4);
    if (threadIdx.x == 255) bsum[blockIdx.x] = s;
}

// merged: each block redundantly reduces bsum[0..b) for its own offset (L2-hot, trivial),
// then scans its 256-chunk -> pscan. Replaces the separate 1-block scan_bsums2 dispatch.
__global__ __launch_bounds__(256) void scan_final2_kernel(const int* __restrict__ partials,
                                                          const int* __restrict__ bsum,
                                                          int* __restrict__ pscan) {
    __shared__ int sh4[4];
    __shared__ int bofs_sh;
    int b = blockIdx.x, tid = threadIdx.x;
    int pv = (tid < NBLKS && tid < b) ? bsum[tid] : 0;
    int ps = block_incl_scan(pv, sh4);
    if (tid == 255) bofs_sh = ps;          // total of bsum[0..b)
    __syncthreads();
    int i = b * 256 + tid;
    int v = (i < PARTN) ? partials[i] : 0;
    int s = block_incl_scan(v, sh4);
    if (i < PARTN) pscan[i] = bofs_sh + s - v;
}

// ---------------- MFMA GEMM body: Hf = f16(X @ W); a_s/a_d from folded att cols ----------------
template<bool BF16IN>
__device__ inline void gemm_body(ushort* __restrict__ Abf, int tid, int r0,
                                 const void* __restrict__ Xv_, const ushort* __restrict__ Wt,
                                 ushort* __restrict__ Hf, float* __restrict__ a_s,
                                 float* __restrict__ a_d, int nrows) {
    int rleft = nrows - r0;
    if (BF16IN) {
        const uint4* Xv = (const uint4*)((const ushort*)Xv_ + (size_t)r0 * NF);  // 8 bf16/uint4
        #pragma unroll
        for (int p = 0; p < 4; ++p) {
            int i = p * 256 + tid;
            int row = i >> 4, c8 = i & 15;
            uint4 v = (row < rleft) ? Xv[row * 16 + c8] : make_uint4(0u, 0u, 0u, 0u);
            *(uint4*)&Abf[row * ASTRIDE + c8 * 8] = v;
        }
    } else {
        const float4* Xv = (const float4*)((const float*)Xv_ + (size_t)r0 * NF);
        #pragma unroll
        for (int p = 0; p < 8; ++p) {
            int i = p * 256 + tid;
            int row = i >> 5, c4 = i & 31;
            float4 v = (row < rleft) ? Xv[row * 32 + c4] : make_float4(0.f, 0.f, 0.f, 0.f);
            ushort4 hv;
            hv.x = rne_bf16(v.x); hv.y = rne_bf16(v.y);
            hv.z = rne_bf16(v.z); hv.w = rne_bf16(v.w);
            *(ushort4*)&Abf[row * ASTRIDE + c4 * 4] = hv;
        }
    }
    __syncthreads();

    int wv = tid >> 6;
    int l = tid & 63;
    int lr = l & 15;
    int lk = l >> 4;
    int rowb = wv * 16;

    short8v a[4];
    #pragma unroll
    for (int kc = 0; kc < 4; ++kc)
        a[kc] = *(const short8v*)&Abf[(rowb + lr) * ASTRIDE + kc * 32 + lk * 8];

    f32x4 acc[9];
    #pragma unroll
    for (int ct = 0; ct < 9; ++ct) acc[ct] = (f32x4){0.f, 0.f, 0.f, 0.f};

    #pragma unroll
    for (int ct = 0; ct < 9; ++ct) {
        #pragma unroll
        for (int kc = 0; kc < 4; ++kc) {
            short8v b = *(const short8v*)&Wt[(ct * 16 + lr) * 144 + kc * 32 + lk * 8];
            acc[ct] = __builtin_amdgcn_mfma_f32_16x16x32_bf16(a[kc], b, acc[ct], 0, 0, 0);
        }
    }

    int rbase = r0 + rowb + lk * 4;
    #pragma unroll
    for (int ct = 0; ct < 8; ++ct) {
        int col = ct * 16 + lr;
        #pragma unroll
        for (int ri = 0; ri < 4; ++ri) {
            int r = rbase + ri;
            if (r < nrows) Hf[(size_t)r * NF + col] = __half_as_ushort(__float2half(acc[ct][ri]));
        }
    }
    if (lr < 8) {
        #pragma unroll
        for (int ri = 0; ri < 4; ++ri) {
            int r = rbase + ri;
            if (r < nrows) {
                if (lr < 4) a_s[(size_t)r * 4 + lr] = acc[8][ri];
                else        a_d[(size_t)r * 4 + (lr - 4)] = acc[8][ri];
            }
        }
    }
}

// ---------------- K3: edge scatter(208) | gemm layer-1(782) ----------------
__global__ __launch_bounds__(256) void mid_kernel(const int* __restrict__ adj,
                                                  const int* __restrict__ pscan,
                                                  int2* __restrict__ ebuf,
                                                  const float* __restrict__ X,
                                                  const ushort* __restrict__ Wt,
                                                  ushort* __restrict__ Hf,
                                                  float* __restrict__ a_s,
                                                  float* __restrict__ a_d, int nrows) {
    __shared__ ushort Abf[64 * ASTRIDE];   // scatter aliases the first 784B as int counters
    int b = blockIdx.x, tid = threadIdx.x;
    if (b < NBLKA) {
        int* lc = (int*)Abf;
        for (int i = tid; i < NBUCK; i += 256) lc[i] = 0;
        __syncthreads();
        int base = b * EPB;
        #pragma unroll
        for (int i = 0; i < EPB / 256; ++i) {
            int e = base + i * 256 + tid;
            if (e < ETOT) {
                int src, dst;
                if (e < E_EDGES) { src = adj[e]; dst = adj[E_EDGES + e]; }
                else             { src = dst = e - E_EDGES; }
                int bk = dst >> 8;
                int r = atomicAdd(&lc[bk], 1);
                ebuf[pscan[bk * NBLKA + b] + r] = make_int2(src, dst);
            }
        }
    } else {
        gemm_body<false>(Abf, tid, (b - NBLKA) * 64, X, Wt, Hf, a_s, a_d, nrows);
    }
}

// ---------------- K5: standalone gemm (layer 2, bf16 input) ----------------
__global__ __launch_bounds__(256) void gemm_mfma_kernel(const void* __restrict__ Xv_,
                                                        const ushort* __restrict__ Wt,
                                                        ushort* __restrict__ Hf,
                                                        float* __restrict__ a_s,
                                                        float* __restrict__ a_d, int nrows) {
    __shared__ ushort Abf[64 * ASTRIDE];
    gemm_body<true>(Abf, threadIdx.x, blockIdx.x * 64, Xv_, Wt, Hf, a_s, a_d, nrows);
}

// ---------------- K4: per-bucket dst ranks -> cnt + slots ----------------
__global__ __launch_bounds__(256) void pass_build_kernel(const int2* __restrict__ ebuf,
                                                         const int* __restrict__ pscan,
                                                         int* __restrict__ cnt,
                                                         int* __restrict__ slots) {
    __shared__ int lc[256];
    int tid = threadIdx.x;
    int b = blockIdx.x;
    lc[tid] = 0;
    __syncthreads();
    int base = pscan[b * NBLKA];
    int end  = (b == NBUCK - 1) ? ETOT : pscan[(b + 1) * NBLKA];
    for (int e = base + tid; e < end; e += 256) {
        int2 sd = ebuf[e];
        int d = sd.y & 255;
        int r = atomicAdd(&lc[d], 1);
        slots[(size_t)sd.y * CAP + r] = sd.x;
    }
    __syncthreads();
    int dst = b * 256 + tid;
    if (dst < N_NODES) cnt[dst] = lc[tid];
}

// ---------------- per-node softmax + aggregation, quarter-per-edge, granule 8 ----------------
template<int WRITE_BF16>
__global__ __launch_bounds__(256) void agg_kernel(const ushort* __restrict__ Hf,
                                                  const float* __restrict__ a_s,
                                                  const float* __restrict__ a_d,
                                                  const int* __restrict__ cnt,
                                                  const int* __restrict__ slots,
                                                  const float* __restrict__ bias,
                                                  void* __restrict__ Out) {
    int lane = threadIdx.x & 63;
    int node = blockIdx.x * 4 + (threadIdx.x >> 6);
    if (node >= N_NODES) return;
    int q = lane >> 4;
    int t = lane & 15;
    int h = t >> 2;
    float adn = a_d[node * 4 + h];
    int deg = cnt[node];
    const int* row = slots + (size_t)node * CAP;
    const uint4* H4 = (const uint4*)Hf;
    float acc[8];
    #pragma unroll
    for (int k = 0; k < 8; ++k) acc[k] = 0.f;
    float denom = 0.f;

    for (int j = 0; j < deg; j += 8) {
        int sv[2]; float ev[2]; uint4 hv[2]; bool ok[2];
        #pragma unroll
        for (int u = 0; u < 2; ++u) {
            int idx = j + u * 4 + q;
            ok[u] = idx < deg;
            sv[u] = row[ok[u] ? idx : 0];
        }
        #pragma unroll
        for (int u = 0; u < 2; ++u) ev[u] = a_s[sv[u] * 4 + h];
        #pragma unroll
        for (int u = 0; u < 2; ++u) hv[u] = H4[(size_t)sv[u] * 16 + t];
        #pragma unroll
        for (int u = 0; u < 2; ++u) {
            float e = ev[u] + adn;
            e = (e > 0.f) ? e : 0.2f * e;          // leaky_relu (log2e scale commutes)
            float w = ok[u] ? exp2f(e) : 0.f;      // |e| small; no max-subtraction needed
            denom += w;
            acc[0] = fmaf(h2f_lo(hv[u].x), w, acc[0]);
            acc[1] = fmaf(h2f_hi(hv[u].x), w, acc[1]);
            acc[2] = fmaf(h2f_lo(hv[u].y), w, acc[2]);
            acc[3] = fmaf(h2f_hi(hv[u].y), w, acc[3]);
            acc[4] = fmaf(h2f_lo(hv[u].z), w, acc[4]);
            acc[5] = fmaf(h2f_hi(hv[u].z), w, acc[5]);
            acc[6] = fmaf(h2f_lo(hv[u].w), w, acc[6]);
            acc[7] = fmaf(h2f_hi(hv[u].w), w, acc[7]);
        }
    }
    #pragma unroll
    for (int ofs = 16; ofs < 64; ofs <<= 1) {
        denom += __shfl_xor(denom, ofs);
        #pragma unroll
        for (int k = 0; k < 8; ++k) acc[k] += __shfl_xor(acc[k], ofs);
    }
    if (q == 0) {
        float inv = 1.f / (denom + 1e-16f);
        float4 b0 = ((const float4*)bias)[t * 2];
        float4 b1 = ((const float4*)bias)[t * 2 + 1];
        float v0 = acc[0] * inv + b0.x, v1 = acc[1] * inv + b0.y;
        float v2 = acc[2] * inv + b0.z, v3 = acc[3] * inv + b0.w;
        float v4 = acc[4] * inv + b1.x, v5 = acc[5] * inv + b1.y;
        float v6 = acc[6] * inv + b1.z, v7 = acc[7] * inv + b1.w;
        if (WRITE_BF16) {
            v0 = fmaxf(v0, 0.f); v1 = fmaxf(v1, 0.f); v2 = fmaxf(v2, 0.f); v3 = fmaxf(v3, 0.f);
            v4 = fmaxf(v4, 0.f); v5 = fmaxf(v5, 0.f); v6 = fmaxf(v6, 0.f); v7 = fmaxf(v7, 0.f);
            uint4 pv;
            pv.x = (uint)rne_bf16(v0) | ((uint)rne_bf16(v1) << 16);
            pv.y = (uint)rne_bf16(v2) | ((uint)rne_bf16(v3) << 16);
            pv.z = (uint)rne_bf16(v4) | ((uint)rne_bf16(v5) << 16);
            pv.w = (uint)rne_bf16(v6) | ((uint)rne_bf16(v7) << 16);
            ((uint4*)((ushort*)Out + (size_t)node * NF))[t] = pv;
        } else {
            float4* orow = (float4*)((float*)Out + (size_t)node * NF);
            orow[t * 2]     = make_float4(v0, v1, v2, v3);
            orow[t * 2 + 1] = make_float4(v4, v5, v6, v7);
        }
    }
}

extern "C" void kernel_launch(void* const* d_in, const int* in_sizes, int n_in,
                              void* d_out, int out_size, void* d_ws, size_t ws_size,
                              hipStream_t stream) {
    const float* x        = (const float*)d_in[0];
    const int*   adj      = (const int*)  d_in[1];
    const float* W1       = (const float*)d_in[2];
    const float* att_src1 = (const float*)d_in[3];
    const float* att_dst1 = (const float*)d_in[4];
    const float* b1       = (const float*)d_in[5];
    const float* W2       = (const float*)d_in[6];
    const float* att_src2 = (const float*)d_in[7];
    const float* att_dst2 = (const float*)d_in[8];
    const float* b2       = (const float*)d_in[9];
    float* out = (float*)d_out;

    // workspace layout
    float* a_s  = (float*)d_ws;                            // N*4
    float* a_d  = a_s + (size_t)N_NODES * HEADS;           // N*4
    ushort* Hf  = (ushort*)(a_d + (size_t)N_NODES * HEADS);// N*128 f16
    ushort* obf = Hf + (size_t)N_NODES * NF;               // N*128 bf16 (inter-layer)
    ushort* Wt1 = obf + (size_t)N_NODES * NF;              // 144*144 bf16
    ushort* Wt2 = Wt1 + 144 * 144;                         // 144*144 bf16
    int* cnt     = (int*)(Wt2 + 144 * 144);                // N
    int* slots   = cnt + N_NODES;                          // N*CAP
    int* partials= slots + (size_t)N_NODES * CAP;          // PARTN
    int* pscan   = partials + PARTN;                       // PARTN
    int* bsum    = pscan + PARTN;                          // NBLKS
    int2* ebuf   = (int2*)(bsum + NBLKS + 3);              // ETOT (8B aligned)

    // K1: bucket histogram | wconv W1 | wconv W2
    prep_kernel<<<NBLKA + 2 * WCB, 256, 0, stream>>>(adj, partials,
                                                     W1, att_src1, att_dst1, Wt1,
                                                     W2, att_src2, att_dst2, Wt2);
    // K2: chunk sums; K3: merged (inline bofs) final scan
    bsum2_kernel<<<NBLKS, 256, 0, stream>>>(partials, bsum);
    scan_final2_kernel<<<NBLKS, 256, 0, stream>>>(partials, bsum, pscan);
    // K4: bucket-sort edges | gemm layer 1
    mid_kernel<<<NBLKA + (N_NODES + 63) / 64, 256, 0, stream>>>(adj, pscan, ebuf,
                                                                x, Wt1, Hf, a_s, a_d, N_NODES);
    // K5: per-dst ranks -> cnt + slots
    pass_build_kernel<<<NBUCK, 256, 0, stream>>>(ebuf, pscan, cnt, slots);
    // K6: agg layer 1 (relu, bf16 out)
    agg_kernel<1><<<(N_NODES + 3) / 4, 256, 0, stream>>>(Hf, a_s, a_d, cnt, slots, b1, obf);
    // K7: gemm layer 2
    gemm_mfma_kernel<<<(N_NODES + 63) / 64, 256, 0, stream>>>(obf, Wt2, Hf, a_s, a_d, N_NODES);
    // K8: agg layer 2 (fp32 out)
    agg_kernel<0><<<(N_NODES + 3) / 4, 256, 0, stream>>>(Hf, a_s, a_d, cnt, slots, b2, out);
}